// Round 21
// baseline (161.304 us; speedup 1.0000x reference)
//
#include <hip/hip_runtime.h>
#include <hip/hip_bf16.h>

#define N_NODES 50000
#define N_EDGES 1600000
#define E_TOT   1650000   // edges + self loops
#define F_IN    128
#define HID     32
#define HEADS   3
#define C1      96        // HEADS*HID
#define OUT_F   16
#define NEG_SLOPE 0.2f
#define BM      32        // l1_gemm node tile (23KB LDS union, 6 blocks/CU)
#define CK      16        // l1_gemm W-chunk k-rows
#define NBUCK   196       // CSR coarse buckets: bucket = dst >> 8 (256 nodes each)
#define CAP     12288     // fixed bucket capacity (mean 8418 -> safe)
#define CHUNK   4096      // edges per block in bucket pass
#define NBLK_B  403       // ceil(E_TOT / CHUNK)
#define NBLK_G  1563      // ceil(N_NODES / BM)

// native clang vectors for nontemporal builtins (HIP_vector_type is rejected)
typedef float f32x4 __attribute__((ext_vector_type(4)));
typedef int   i32x2 __attribute__((ext_vector_type(2)));

__device__ __forceinline__ int ntload_i(const int* p) {
    return __builtin_nontemporal_load(p);
}
__device__ __forceinline__ float4 ntload_f4(const float4* p) {
    f32x4 v = __builtin_nontemporal_load((const f32x4*)p);
    return make_float4(v.x, v.y, v.z, v.w);
}
__device__ __forceinline__ int2 ntload_i2(const int2* p) {
    i32x2 v = __builtin_nontemporal_load((const i32x2*)p);
    return make_int2(v.x, v.y);
}

__device__ __forceinline__ float lrelu(float v) {
    return v > 0.f ? v : NEG_SLOPE * v;
}
__device__ __forceinline__ float wave_sum(float v) {
#pragma unroll
    for (int o = 32; o; o >>= 1) v += __shfl_xor(v, o);
    return v;
}

// ================= phase1: k_bucket (blocks 0..402) ∥ l1_gemm (blocks 403..) ======
__device__ void bucket_body(char* smem, int bid,
                            const int* __restrict__ src, const int* __restrict__ dst,
                            int* __restrict__ gcur, int* __restrict__ bedge) {
    int* h    = (int*)smem;          // [256]
    int* sc   = h + 256;
    int* cur  = sc + 256;
    int* dstg = cur + 256;
    int* ebuf = dstg + 256;          // [CHUNK] 16KB
    int t = threadIdx.x;
    h[t] = 0; dstg[t] = 0;
    __syncthreads();
    int base = bid * CHUNK;
    int end = min(base + CHUNK, E_TOT);
    for (int e = base + t; e < end; e += 256) {
        int d = (e < N_EDGES) ? dst[e] : e - N_EDGES;
        atomicAdd(&h[d >> 8], 1);
    }
    __syncthreads();
    int v = h[t];
    sc[t] = v; __syncthreads();
#pragma unroll
    for (int o = 1; o < 256; o <<= 1) {
        int u = (t >= o) ? sc[t - o] : 0;
        __syncthreads();
        sc[t] += u;
        __syncthreads();
    }
    cur[t] = sc[t] - v;
    if (t < NBUCK && v) dstg[t] = t * CAP + atomicAdd(&gcur[t], v);
    __syncthreads();
    for (int e = base + t; e < end; e += 256) {
        int s, d;
        if (e < N_EDGES) { s = src[e]; d = dst[e]; }
        else { s = d = e - N_EDGES; }
        int slot = atomicAdd(&cur[d >> 8], 1);
        ebuf[slot] = (s << 8) | (d & 255);
    }
    __syncthreads();
    int wv = t >> 6, lane = t & 63;
    for (int b = wv; b < NBUCK; b += 4) {
        int len = h[b];
        int st = sc[b] - len;
        int dg = dstg[b];
        for (int k = lane; k < len; k += 64)
            bedge[dg + k] = ebuf[st + k];
    }
}

__device__ void gemm_body(char* smem, int bid,
                          const float* __restrict__ x, const float* __restrict__ W1,
                          const float* __restrict__ attS, const float* __restrict__ attD,
                          unsigned char* __restrict__ h1,
                          float* __restrict__ aS1p, float* __restrict__ aD1p) {
    float (*xs)[F_IN + 4] = (float (*)[F_IN + 4])smem;        // 32 x 132 x4 = 16896B
    float* ws = (float*)(smem + BM * (F_IN + 4) * 4);         // CK*C1*4 = 6144B
    int t = threadIdx.x;
    int tx = t & 15, ty = t >> 4;
    int n0 = bid * BM;
    {
        const float4* xg = (const float4*)x;
#pragma unroll
        for (int it = 0; it < 4; ++it) {
            int idx = t + it * 256;
            int r = idx >> 5, c = idx & 31;
            int nn = n0 + r;
            float4 v = (nn < N_NODES) ? ntload_f4(&xg[nn * 32 + c])
                                      : make_float4(0.f, 0.f, 0.f, 0.f);
            *(float4*)&xs[r][c * 4] = v;
        }
    }

    float acc[2][6];
#pragma unroll
    for (int i = 0; i < 2; ++i)
#pragma unroll
        for (int j = 0; j < 6; ++j) acc[i][j] = 0.f;

    int r0 = ty * 2;
    for (int c = 0; c < F_IN / CK; ++c) {
        __syncthreads();
        {
            const float2* wg = (const float2*)(W1 + c * CK * C1);
#pragma unroll
            for (int i = 0; i < 3; ++i) {
                int idx = t + i * 256;
                ((float2*)ws)[idx] = wg[idx];
            }
        }
        __syncthreads();
        int kb = c * CK;
#pragma unroll
        for (int kk = 0; kk < CK; kk += 2) {
            float2 w0[3], w1[3];
#pragma unroll
            for (int p = 0; p < 3; ++p) {
                w0[p] = *(const float2*)&ws[kk * C1 + 2 * tx + 32 * p];
                w1[p] = *(const float2*)&ws[(kk + 1) * C1 + 2 * tx + 32 * p];
            }
            float2 xv[2];
#pragma unroll
            for (int i = 0; i < 2; ++i)
                xv[i] = *(const float2*)&xs[r0 + i][kb + kk];
#pragma unroll
            for (int i = 0; i < 2; ++i)
#pragma unroll
                for (int p = 0; p < 3; ++p) {
                    acc[i][2 * p]     = fmaf(xv[i].x, w0[p].x, acc[i][2 * p]);
                    acc[i][2 * p + 1] = fmaf(xv[i].x, w0[p].y, acc[i][2 * p + 1]);
                    acc[i][2 * p]     = fmaf(xv[i].y, w1[p].x, acc[i][2 * p]);
                    acc[i][2 * p + 1] = fmaf(xv[i].y, w1[p].y, acc[i][2 * p + 1]);
                }
        }
    }

    float as[6], ad[6];
#pragma unroll
    for (int p = 0; p < 3; ++p) {
        *(float2*)&as[2 * p] = *(const float2*)&attS[2 * tx + 32 * p];
        *(float2*)&ad[2 * p] = *(const float2*)&attD[2 * tx + 32 * p];
    }
#pragma unroll
    for (int i = 0; i < 2; ++i) {
        int n = n0 + r0 + i;
        bool ok = (n < N_NODES);
        float ps[3], pd[3];
#pragma unroll
        for (int p = 0; p < 3; ++p) {
            int packed = __builtin_amdgcn_cvt_pk_fp8_f32(acc[i][2 * p], acc[i][2 * p + 1], 0, false);
            if (ok) *(unsigned short*)&h1[n * C1 + 2 * tx + 32 * p] = (unsigned short)packed;
            ps[p] = acc[i][2 * p] * as[2 * p] + acc[i][2 * p + 1] * as[2 * p + 1];
            pd[p] = acc[i][2 * p] * ad[2 * p] + acc[i][2 * p + 1] * ad[2 * p + 1];
        }
#pragma unroll
        for (int o = 1; o < 16; o <<= 1) {
#pragma unroll
            for (int p = 0; p < 3; ++p) {
                ps[p] += __shfl_xor(ps[p], o);
                pd[p] += __shfl_xor(pd[p], o);
            }
        }
        if (ok && tx == 0) {
            aS1p[n * 4 + 0] = ps[0]; aS1p[n * 4 + 1] = ps[1]; aS1p[n * 4 + 2] = ps[2];
            aS1p[n * 4 + 3] = 0.f;
            aD1p[n * 4 + 0] = pd[0]; aD1p[n * 4 + 1] = pd[1]; aD1p[n * 4 + 2] = pd[2];
            aD1p[n * 4 + 3] = 0.f;
        }
    }
}

__global__ __launch_bounds__(256) void phase1(const int* __restrict__ src,
                                              const int* __restrict__ dst,
                                              int* __restrict__ gcur,
                                              int* __restrict__ bedge,
                                              const float* __restrict__ x,
                                              const float* __restrict__ W1,
                                              const float* __restrict__ attS,
                                              const float* __restrict__ attD,
                                              unsigned char* __restrict__ h1,
                                              float* __restrict__ aS1p,
                                              float* __restrict__ aD1p) {
    __shared__ __align__(16) char smem[BM * (F_IN + 4) * 4 + CK * C1 * 4];  // 23040B
    if (blockIdx.x < NBLK_B)
        bucket_body(smem, blockIdx.x, src, dst, gcur, bedge);
    else
        gemm_body(smem, blockIdx.x - NBLK_B, x, W1, attS, attD, h1, aS1p, aD1p);
}

// ===== k_finalize: stage bucket run in LDS once; hist+scan+scatter from LDS =====
__global__ __launch_bounds__(256) void k_finalize(const int* __restrict__ gcur,
                                                  const int* __restrict__ bedge,
                                                  int2* __restrict__ rw,
                                                  int* __restrict__ csr) {
    __shared__ int h[256];
    __shared__ int sc[256];
    __shared__ int cur[256];
    __shared__ int ebuf[CAP];            // 48KB
    int b = blockIdx.x, t = threadIdx.x;
    h[t] = 0; __syncthreads();
    int s0 = b * CAP;
    int len = gcur[b];
    for (int i = t; i < len; i += 256) {
        int p = ntload_i(&bedge[s0 + i]);
        ebuf[i] = p;
        atomicAdd(&h[p & 255], 1);
    }
    __syncthreads();
    int v = h[t];
    sc[t] = v; __syncthreads();
#pragma unroll
    for (int o = 1; o < 256; o <<= 1) {
        int u = (t >= o) ? sc[t - o] : 0;
        __syncthreads();
        sc[t] += u;
        __syncthreads();
    }
    int base = s0 + sc[t] - v;
    int n = b * 256 + t;
    if (n < N_NODES) rw[n] = make_int2(base, base + v);
    cur[t] = base;
    __syncthreads();
    for (int i = t; i < len; i += 256) {
        int p = ebuf[i];
        int slot = atomicAdd(&cur[p & 255], 1);
        csr[slot] = ((unsigned)p) >> 8;
    }
}

// ===== Layer 1 fused: wave-PAIR per node. sub0 stages tile + denoms; both waves
// consume alternating 8-edge batches; partial accs combined via LDS; sub0 epilogue.
__global__ __launch_bounds__(256) void l1_node(const int2* __restrict__ rw,
                                               const int* __restrict__ csr,
                                               const unsigned char* __restrict__ h1,
                                               const float* __restrict__ aS1p,
                                               const float* __restrict__ aD1p,
                                               const float* __restrict__ bias1,
                                               const float* __restrict__ W2,
                                               const float* __restrict__ attS2,
                                               const float* __restrict__ attD2,
                                               float* __restrict__ h2,
                                               float* __restrict__ aS2,
                                               float* __restrict__ aD2) {
    __shared__ float lds[2][3][66][2];   // [pair][head][entry(16B rows)][{e, s*96}]
    __shared__ float xsh[2][100];        // per-pair hmid row
    __shared__ float pacc[4][48][2];     // per-wave partial accumulators
    int wv = threadIdx.x >> 6, lane = threadIdx.x & 63;
    int pr = wv >> 1, sub = wv & 1;      // pair id, member id
    int nA = blockIdx.x * 2;
    int n = nA + pr;
    int2 ra = ntload_i2(&rw[nA]);
    int2 rb = ntload_i2(&rw[nA + 1]);
    int rs = pr ? rb.x : ra.x;
    int re = pr ? rb.y : ra.y;
    int tA = (ra.y - ra.x + 63) >> 6;
    int tB = (rb.y - rb.x + 63) >> 6;
    int maxT = max(tA, tB);
    float4 adv = *(const float4*)&aD1p[n * 4];
    int f0 = (lane < 48) ? lane * 2 : 0;
    int hh = lane >> 4; if (hh > 2) hh = 2;
    float d0 = 0.f, d1 = 0.f, d2 = 0.f;
    float acc0 = 0.f, acc1 = 0.f;
    for (int t = 0; t < maxT; ++t) {
        int base = rs + t * 64;
        if (sub == 0 && base < re) {
            int j = base + lane;
            float e0 = 0.f, e1 = 0.f, e2 = 0.f;
            float sf = __int_as_float(0);
            if (j < re) {
                int s = ntload_i(&csr[j]);
                float4 a = *(const float4*)&aS1p[s * 4];
                e0 = __expf(lrelu(a.x + adv.x));
                e1 = __expf(lrelu(a.y + adv.y));
                e2 = __expf(lrelu(a.z + adv.z));
                sf = __int_as_float(s * C1);
            }
            d0 += e0; d1 += e1; d2 += e2;
            lds[pr][0][lane][0] = e0; lds[pr][0][lane][1] = sf;
            lds[pr][1][lane][0] = e1; lds[pr][1][lane][1] = sf;
            lds[pr][2][lane][0] = e2; lds[pr][2][lane][1] = sf;
        }
        __syncthreads();
        if (base < re) {
            int cnt8 = (min(64, re - base) + 7) & ~7;
            for (int j2 = sub * 8; j2 < cnt8; j2 += 16) {
                float4 q[4];   // 2 edges per float4
#pragma unroll
                for (int u2 = 0; u2 < 4; ++u2)
                    q[u2] = *(const float4*)&lds[pr][hh][j2 + 2 * u2][0];
                unsigned short hv[8];
#pragma unroll
                for (int u2 = 0; u2 < 4; ++u2) {
                    hv[2 * u2]     = *(const unsigned short*)&h1[__float_as_int(q[u2].y) + f0];
                    hv[2 * u2 + 1] = *(const unsigned short*)&h1[__float_as_int(q[u2].w) + f0];
                }
#pragma unroll
                for (int u2 = 0; u2 < 4; ++u2) {
                    auto fa = __builtin_amdgcn_cvt_pk_f32_fp8((int)hv[2 * u2], false);
                    auto fb = __builtin_amdgcn_cvt_pk_f32_fp8((int)hv[2 * u2 + 1], false);
                    acc0 = fmaf(fa[0], q[u2].x, acc0);
                    acc1 = fmaf(fa[1], q[u2].x, acc1);
                    acc0 = fmaf(fb[0], q[u2].z, acc0);
                    acc1 = fmaf(fb[1], q[u2].z, acc1);
                }
            }
        }
        __syncthreads();
    }
    d0 = wave_sum(d0); d1 = wave_sum(d1); d2 = wave_sum(d2);  // full denoms in sub0
    if (lane < 48) { pacc[wv][lane][0] = acc0; pacc[wv][lane][1] = acc1; }
    __syncthreads();
    if (sub == 0) {
        if (lane < 48) {
            acc0 += pacc[wv + 1][lane][0];
            acc1 += pacc[wv + 1][lane][1];
            float den = (hh == 0) ? d0 : (hh == 1) ? d1 : d2;
            float r = 1.f / den;
            float v0 = acc0 * r + bias1[f0];
            float v1 = acc1 * r + bias1[f0 + 1];
            xsh[pr][f0]     = v0 > 0.f ? v0 : 0.f;
            xsh[pr][f0 + 1] = v1 > 0.f ? v1 : 0.f;
        }
        // fused layer-2 GEMV (96->16) + attention dots (wave-coherent, no barrier:
        // xsh written and read by the same wave's lanes via LDS, __shfl covers rest)
        int g = lane >> 4, o2 = lane & 15;
        const float* wp2 = W2 + o2;
        float a2 = 0.f;
#pragma unroll
        for (int kk = 0; kk < 24; ++kk) {
            int k = g * 24 + kk;
            a2 = fmaf(xsh[pr][k], wp2[k * OUT_F], a2);
        }
        a2 += __shfl_xor(a2, 16);
        a2 += __shfl_xor(a2, 32);
        float ps = a2 * attS2[o2];
        float pd = a2 * attD2[o2];
#pragma unroll
        for (int o = 1; o < 16; o <<= 1) {
            ps += __shfl_xor(ps, o);
            pd += __shfl_xor(pd, o);
        }
        if (lane == 0) { aS2[n] = ps; aD2[n] = pd; }
        if (lane < 16) h2[n * OUT_F + o2] = a2;
    }
}

// ===== Layer 2 fused softmax+aggregate+bias+log_softmax: 1 wave/node, f4 LDS =====
__global__ __launch_bounds__(256) void l2_node(const int2* __restrict__ rw,
                                               const int* __restrict__ csr,
                                               const float* __restrict__ h2,
                                               const float* __restrict__ aS2,
                                               const float* __restrict__ aD2,
                                               const float* __restrict__ bias2,
                                               float* __restrict__ out) {
    __shared__ float lds[4][66][2];      // [wave][entry(16B rows)][{e, s*16}]
    int wv = threadIdx.x >> 6, lane = threadIdx.x & 63;
    int n = blockIdx.x * 4 + wv;
    int2 r2 = ntload_i2(&rw[n]);
    int rs = r2.x, re = r2.y;
    float adn = aD2[n];
    int g = lane >> 4, fl = lane & 15;
    float den = 0.f, acc = 0.f;
    for (int base = rs; base < re; base += 64) {
        int j = base + lane;
        float e = 0.f;
        float sf = __int_as_float(0);
        if (j < re) {
            int s = ntload_i(&csr[j]);
            e = __expf(lrelu(aS2[s] + adn));
            sf = __int_as_float(s * OUT_F);
        }
        den += e;
        lds[wv][lane][0] = e;
        lds[wv][lane][1] = sf;
        int cnt = min(64, re - base);
#pragma unroll
        for (int b2 = 0; b2 < 2; ++b2) {
            int j0 = g * 16 + b2 * 8;
            if (j0 < cnt) {
                float4 q[4];
#pragma unroll
                for (int u2 = 0; u2 < 4; ++u2)
                    q[u2] = *(const float4*)&lds[wv][j0 + 2 * u2][0];
                float hv[8];
#pragma unroll
                for (int u2 = 0; u2 < 4; ++u2) {
                    hv[2 * u2]     = h2[__float_as_int(q[u2].y) + fl];
                    hv[2 * u2 + 1] = h2[__float_as_int(q[u2].w) + fl];
                }
#pragma unroll
                for (int u2 = 0; u2 < 4; ++u2) {
                    acc = fmaf(hv[2 * u2],     q[u2].x, acc);
                    acc = fmaf(hv[2 * u2 + 1], q[u2].z, acc);
                }
            }
        }
    }
    den = wave_sum(den);
    acc += __shfl_xor(acc, 16);
    acc += __shfl_xor(acc, 32);
    float v = acc / den + bias2[fl];
    float mm = v;
#pragma unroll
    for (int o = 1; o < 16; o <<= 1) mm = fmaxf(mm, __shfl_xor(mm, o));
    float se = __expf(v - mm);
#pragma unroll
    for (int o = 1; o < 16; o <<= 1) se += __shfl_xor(se, o);
    float lse = mm + logf(se);
    if (lane < 16) __builtin_nontemporal_store(v - lse, &out[n * OUT_F + fl]);
}

extern "C" void kernel_launch(void* const* d_in, const int* in_sizes, int n_in,
                              void* d_out, int out_size, void* d_ws, size_t ws_size,
                              hipStream_t stream) {
    const float* x      = (const float*)d_in[0];
    const int*   ei     = (const int*)  d_in[1];
    const float* W1     = (const float*)d_in[2];
    const float* attS1  = (const float*)d_in[3];
    const float* attD1  = (const float*)d_in[4];
    const float* bias1  = (const float*)d_in[5];
    const float* W2     = (const float*)d_in[6];
    const float* attS2  = (const float*)d_in[7];
    const float* attD2  = (const float*)d_in[8];
    const float* bias2  = (const float*)d_in[9];
    const int* src = ei;
    const int* dst = ei + N_EDGES;
    float* out = (float*)d_out;
    (void)in_sizes; (void)n_in; (void)out_size; (void)ws_size;

    // ---- workspace layout ----
    char* wsb = (char*)d_ws;
    size_t off = 0;
    int* gcur   = (int*)(wsb + off); off += 256 * 4;          // zero region
    size_t zero_bytes = off;
    int2* rw    = (int2*)(wsb + off); off += (size_t)N_NODES * 8;
    off = (off + 15) & ~(size_t)15;
    int* csr    = (int*)(wsb + off); off += (size_t)NBUCK * CAP * 4;
    off = (off + 15) & ~(size_t)15;
    int* bedge  = (int*)(wsb + off); off += (size_t)NBUCK * CAP * 4;
    off = (off + 15) & ~(size_t)15;
    unsigned char* h1 = (unsigned char*)(wsb + off); off += (size_t)N_NODES * C1;
    off = (off + 15) & ~(size_t)15;
    float* aS1p = (float*)(wsb + off); off += (size_t)N_NODES * 4 * 4;
    float* aD1p = (float*)(wsb + off); off += (size_t)N_NODES * 4 * 4;
    off = (off + 15) & ~(size_t)15;
    float* h2   = (float*)(wsb + off); off += (size_t)N_NODES * OUT_F * 4;
    float* aS2  = (float*)(wsb + off); off += (size_t)N_NODES * 4;
    float* aD2  = (float*)(wsb + off); off += (size_t)N_NODES * 4;

    hipMemsetAsync(d_ws, 0, zero_bytes, stream);

    // phase1: CSR bucket pass ∥ layer-1 GEMM (independent, one dispatch)
    phase1<<<NBLK_B + NBLK_G, 256, 0, stream>>>(src, dst, gcur, bedge,
                                                x, W1, attS1, attD1, h1, aS1p, aD1p);
    k_finalize<<<NBUCK, 256, 0, stream>>>(gcur, bedge, rw, csr);

    l1_node<<<N_NODES / 2, 256, 0, stream>>>(rw, csr, h1, aS1p, aD1p, bias1,
                                             W2, attS2, attD2, h2, aS2, aD2);
    l2_node<<<N_NODES / 4, 256, 0, stream>>>(rw, csr, h2, aS2, aD2, bias2, out);
}

// Round 22
// 148.603 us; speedup vs baseline: 1.0855x; 1.0855x over previous
//
#include <hip/hip_runtime.h>
#include <hip/hip_bf16.h>

#define N_NODES 50000
#define N_EDGES 1600000
#define E_TOT   1650000   // edges + self loops
#define F_IN    128
#define HID     32
#define HEADS   3
#define C1      96        // HEADS*HID
#define OUT_F   16
#define NEG_SLOPE 0.2f
#define BM      32        // l1_gemm node tile (23KB LDS union, 6 blocks/CU)
#define CK      16        // l1_gemm W-chunk k-rows
#define NBUCK   196       // CSR coarse buckets: bucket = dst >> 8 (256 nodes each)
#define CAP     12288     // fixed bucket capacity (mean 8418 -> safe)
#define CHUNK   4096      // edges per block in bucket pass
#define NBLK_B  403       // ceil(E_TOT / CHUNK)
#define NBLK_G  1563      // ceil(N_NODES / BM)

// native clang vectors for nontemporal builtins (HIP_vector_type is rejected)
typedef float f32x4 __attribute__((ext_vector_type(4)));
typedef int   i32x2 __attribute__((ext_vector_type(2)));

__device__ __forceinline__ int ntload_i(const int* p) {
    return __builtin_nontemporal_load(p);
}
__device__ __forceinline__ float4 ntload_f4(const float4* p) {
    f32x4 v = __builtin_nontemporal_load((const f32x4*)p);
    return make_float4(v.x, v.y, v.z, v.w);
}
__device__ __forceinline__ int2 ntload_i2(const int2* p) {
    i32x2 v = __builtin_nontemporal_load((const i32x2*)p);
    return make_int2(v.x, v.y);
}

__device__ __forceinline__ float lrelu(float v) {
    return v > 0.f ? v : NEG_SLOPE * v;
}
__device__ __forceinline__ float wave_sum(float v) {
#pragma unroll
    for (int o = 32; o; o >>= 1) v += __shfl_xor(v, o);
    return v;
}

// ================= phase1: k_bucket (blocks 0..402) ∥ l1_gemm (blocks 403..) ======
__device__ void bucket_body(char* smem, int bid,
                            const int* __restrict__ src, const int* __restrict__ dst,
                            int* __restrict__ gcur, int* __restrict__ bedge) {
    int* h    = (int*)smem;          // [256]
    int* sc   = h + 256;
    int* cur  = sc + 256;
    int* dstg = cur + 256;
    int* ebuf = dstg + 256;          // [CHUNK] 16KB
    int t = threadIdx.x;
    h[t] = 0; dstg[t] = 0;
    __syncthreads();
    int base = bid * CHUNK;
    int end = min(base + CHUNK, E_TOT);
    for (int e = base + t; e < end; e += 256) {
        int d = (e < N_EDGES) ? dst[e] : e - N_EDGES;
        atomicAdd(&h[d >> 8], 1);
    }
    __syncthreads();
    int v = h[t];
    sc[t] = v; __syncthreads();
#pragma unroll
    for (int o = 1; o < 256; o <<= 1) {
        int u = (t >= o) ? sc[t - o] : 0;
        __syncthreads();
        sc[t] += u;
        __syncthreads();
    }
    cur[t] = sc[t] - v;
    if (t < NBUCK && v) dstg[t] = t * CAP + atomicAdd(&gcur[t], v);
    __syncthreads();
    for (int e = base + t; e < end; e += 256) {
        int s, d;
        if (e < N_EDGES) { s = src[e]; d = dst[e]; }
        else { s = d = e - N_EDGES; }
        int slot = atomicAdd(&cur[d >> 8], 1);
        ebuf[slot] = (s << 8) | (d & 255);
    }
    __syncthreads();
    int wv = t >> 6, lane = t & 63;
    for (int b = wv; b < NBUCK; b += 4) {
        int len = h[b];
        int st = sc[b] - len;
        int dg = dstg[b];
        for (int k = lane; k < len; k += 64)
            bedge[dg + k] = ebuf[st + k];
    }
}

__device__ void gemm_body(char* smem, int bid,
                          const float* __restrict__ x, const float* __restrict__ W1,
                          const float* __restrict__ attS, const float* __restrict__ attD,
                          unsigned char* __restrict__ h1,
                          float* __restrict__ aS1p, float* __restrict__ aD1p) {
    float (*xs)[F_IN + 4] = (float (*)[F_IN + 4])smem;        // 32 x 132 x4 = 16896B
    float* ws = (float*)(smem + BM * (F_IN + 4) * 4);         // CK*C1*4 = 6144B
    int t = threadIdx.x;
    int tx = t & 15, ty = t >> 4;
    int n0 = bid * BM;
    {
        const float4* xg = (const float4*)x;
#pragma unroll
        for (int it = 0; it < 4; ++it) {
            int idx = t + it * 256;
            int r = idx >> 5, c = idx & 31;
            int nn = n0 + r;
            float4 v = (nn < N_NODES) ? ntload_f4(&xg[nn * 32 + c])
                                      : make_float4(0.f, 0.f, 0.f, 0.f);
            *(float4*)&xs[r][c * 4] = v;
        }
    }

    float acc[2][6];
#pragma unroll
    for (int i = 0; i < 2; ++i)
#pragma unroll
        for (int j = 0; j < 6; ++j) acc[i][j] = 0.f;

    int r0 = ty * 2;
    for (int c = 0; c < F_IN / CK; ++c) {
        __syncthreads();
        {
            const float2* wg = (const float2*)(W1 + c * CK * C1);
#pragma unroll
            for (int i = 0; i < 3; ++i) {
                int idx = t + i * 256;
                ((float2*)ws)[idx] = wg[idx];
            }
        }
        __syncthreads();
        int kb = c * CK;
#pragma unroll
        for (int kk = 0; kk < CK; kk += 2) {
            float2 w0[3], w1[3];
#pragma unroll
            for (int p = 0; p < 3; ++p) {
                w0[p] = *(const float2*)&ws[kk * C1 + 2 * tx + 32 * p];
                w1[p] = *(const float2*)&ws[(kk + 1) * C1 + 2 * tx + 32 * p];
            }
            float2 xv[2];
#pragma unroll
            for (int i = 0; i < 2; ++i)
                xv[i] = *(const float2*)&xs[r0 + i][kb + kk];
#pragma unroll
            for (int i = 0; i < 2; ++i)
#pragma unroll
                for (int p = 0; p < 3; ++p) {
                    acc[i][2 * p]     = fmaf(xv[i].x, w0[p].x, acc[i][2 * p]);
                    acc[i][2 * p + 1] = fmaf(xv[i].x, w0[p].y, acc[i][2 * p + 1]);
                    acc[i][2 * p]     = fmaf(xv[i].y, w1[p].x, acc[i][2 * p]);
                    acc[i][2 * p + 1] = fmaf(xv[i].y, w1[p].y, acc[i][2 * p + 1]);
                }
        }
    }

    float as[6], ad[6];
#pragma unroll
    for (int p = 0; p < 3; ++p) {
        *(float2*)&as[2 * p] = *(const float2*)&attS[2 * tx + 32 * p];
        *(float2*)&ad[2 * p] = *(const float2*)&attD[2 * tx + 32 * p];
    }
#pragma unroll
    for (int i = 0; i < 2; ++i) {
        int n = n0 + r0 + i;
        bool ok = (n < N_NODES);
        float ps[3], pd[3];
#pragma unroll
        for (int p = 0; p < 3; ++p) {
            int packed = __builtin_amdgcn_cvt_pk_fp8_f32(acc[i][2 * p], acc[i][2 * p + 1], 0, false);
            if (ok) *(unsigned short*)&h1[n * C1 + 2 * tx + 32 * p] = (unsigned short)packed;
            ps[p] = acc[i][2 * p] * as[2 * p] + acc[i][2 * p + 1] * as[2 * p + 1];
            pd[p] = acc[i][2 * p] * ad[2 * p] + acc[i][2 * p + 1] * ad[2 * p + 1];
        }
#pragma unroll
        for (int o = 1; o < 16; o <<= 1) {
#pragma unroll
            for (int p = 0; p < 3; ++p) {
                ps[p] += __shfl_xor(ps[p], o);
                pd[p] += __shfl_xor(pd[p], o);
            }
        }
        if (ok && tx == 0) {
            aS1p[n * 4 + 0] = ps[0]; aS1p[n * 4 + 1] = ps[1]; aS1p[n * 4 + 2] = ps[2];
            aS1p[n * 4 + 3] = 0.f;
            aD1p[n * 4 + 0] = pd[0]; aD1p[n * 4 + 1] = pd[1]; aD1p[n * 4 + 2] = pd[2];
            aD1p[n * 4 + 3] = 0.f;
        }
    }
}

__global__ __launch_bounds__(256) void phase1(const int* __restrict__ src,
                                              const int* __restrict__ dst,
                                              int* __restrict__ gcur,
                                              int* __restrict__ bedge,
                                              const float* __restrict__ x,
                                              const float* __restrict__ W1,
                                              const float* __restrict__ attS,
                                              const float* __restrict__ attD,
                                              unsigned char* __restrict__ h1,
                                              float* __restrict__ aS1p,
                                              float* __restrict__ aD1p) {
    __shared__ __align__(16) char smem[BM * (F_IN + 4) * 4 + CK * C1 * 4];  // 23040B
    if (blockIdx.x < NBLK_B)
        bucket_body(smem, blockIdx.x, src, dst, gcur, bedge);
    else
        gemm_body(smem, blockIdx.x - NBLK_B, x, W1, attS, attD, h1, aS1p, aD1p);
}

// ===== k_finalize: stage bucket run in LDS once; hist+scan+scatter from LDS =====
__global__ __launch_bounds__(256) void k_finalize(const int* __restrict__ gcur,
                                                  const int* __restrict__ bedge,
                                                  int2* __restrict__ rw,
                                                  int* __restrict__ csr) {
    __shared__ int h[256];
    __shared__ int sc[256];
    __shared__ int cur[256];
    __shared__ int ebuf[CAP];            // 48KB
    int b = blockIdx.x, t = threadIdx.x;
    h[t] = 0; __syncthreads();
    int s0 = b * CAP;
    int len = gcur[b];
    for (int i = t; i < len; i += 256) {
        int p = ntload_i(&bedge[s0 + i]);
        ebuf[i] = p;
        atomicAdd(&h[p & 255], 1);
    }
    __syncthreads();
    int v = h[t];
    sc[t] = v; __syncthreads();
#pragma unroll
    for (int o = 1; o < 256; o <<= 1) {
        int u = (t >= o) ? sc[t - o] : 0;
        __syncthreads();
        sc[t] += u;
        __syncthreads();
    }
    int base = s0 + sc[t] - v;
    int n = b * 256 + t;
    if (n < N_NODES) rw[n] = make_int2(base, base + v);
    cur[t] = base;
    __syncthreads();
    for (int i = t; i < len; i += 256) {
        int p = ebuf[i];
        int slot = atomicAdd(&cur[p & 255], 1);
        csr[slot] = ((unsigned)p) >> 8;
    }
}

// ===== Layer 1 fused: softmax+aggregate (fp8 gather, batch-8, f4 LDS) + l2 GEMV =====
__global__ __launch_bounds__(256) void l1_node(const int2* __restrict__ rw,
                                               const int* __restrict__ csr,
                                               const unsigned char* __restrict__ h1,
                                               const float* __restrict__ aS1p,
                                               const float* __restrict__ aD1p,
                                               const float* __restrict__ bias1,
                                               const float* __restrict__ W2,
                                               const float* __restrict__ attS2,
                                               const float* __restrict__ attD2,
                                               float* __restrict__ h2,
                                               float* __restrict__ aS2,
                                               float* __restrict__ aD2) {
    __shared__ float lds[4][3][66][2];   // [wave][head][entry(+pad, 16B-aligned rows)][{e, s*96}]
    __shared__ float xsh[4][100];        // per-wave hmid row
    int wv = threadIdx.x >> 6, lane = threadIdx.x & 63;
    int n = blockIdx.x * 4 + wv;
    int2 r2 = ntload_i2(&rw[n]);
    int rs = r2.x, re = r2.y;
    float4 adv = *(const float4*)&aD1p[n * 4];
    int f0 = (lane < 48) ? lane * 2 : 0;   // adjacent feature pair
    int hh = lane >> 4; if (hh > 2) hh = 2;
    float d0 = 0.f, d1 = 0.f, d2 = 0.f;
    float acc0 = 0.f, acc1 = 0.f;
    for (int base = rs; base < re; base += 64) {
        int j = base + lane;
        float e0 = 0.f, e1 = 0.f, e2 = 0.f;
        float sf = __int_as_float(0);
        if (j < re) {
            int s = ntload_i(&csr[j]);
            float4 a = *(const float4*)&aS1p[s * 4];
            e0 = __expf(lrelu(a.x + adv.x));
            e1 = __expf(lrelu(a.y + adv.y));
            e2 = __expf(lrelu(a.z + adv.z));
            sf = __int_as_float(s * C1);   // byte offset base (fp8 = 1B/elem)
        }
        d0 += e0; d1 += e1; d2 += e2;
        lds[wv][0][lane][0] = e0; lds[wv][0][lane][1] = sf;
        lds[wv][1][lane][0] = e1; lds[wv][1][lane][1] = sf;
        lds[wv][2][lane][0] = e2; lds[wv][2][lane][1] = sf;
        int cnt8 = (min(64, re - base) + 7) & ~7;
        for (int j2 = 0; j2 < cnt8; j2 += 8) {
            float4 q[4];   // 2 edges per float4
#pragma unroll
            for (int u2 = 0; u2 < 4; ++u2)
                q[u2] = *(const float4*)&lds[wv][hh][j2 + 2 * u2][0];
            unsigned short hv[8];
#pragma unroll
            for (int u2 = 0; u2 < 4; ++u2) {
                hv[2 * u2]     = *(const unsigned short*)&h1[__float_as_int(q[u2].y) + f0];
                hv[2 * u2 + 1] = *(const unsigned short*)&h1[__float_as_int(q[u2].w) + f0];
            }
#pragma unroll
            for (int u2 = 0; u2 < 4; ++u2) {
                auto fa = __builtin_amdgcn_cvt_pk_f32_fp8((int)hv[2 * u2], false);
                auto fb = __builtin_amdgcn_cvt_pk_f32_fp8((int)hv[2 * u2 + 1], false);
                acc0 = fmaf(fa[0], q[u2].x, acc0);
                acc1 = fmaf(fa[1], q[u2].x, acc1);
                acc0 = fmaf(fb[0], q[u2].z, acc0);
                acc1 = fmaf(fb[1], q[u2].z, acc1);
            }
        }
    }
    d0 = wave_sum(d0); d1 = wave_sum(d1); d2 = wave_sum(d2);
    if (lane < 48) {
        float den = (hh == 0) ? d0 : (hh == 1) ? d1 : d2;
        float r = 1.f / den;
        float v0 = acc0 * r + bias1[f0];
        float v1 = acc1 * r + bias1[f0 + 1];
        xsh[wv][f0]     = v0 > 0.f ? v0 : 0.f;
        xsh[wv][f0 + 1] = v1 > 0.f ? v1 : 0.f;
    }
    // ---- fused layer-2 GEMV (96->16) + attention dots; same wave, no barrier ----
    int g = lane >> 4, o2 = lane & 15;
    const float* wp2 = W2 + o2;
    float a2 = 0.f;
#pragma unroll
    for (int kk = 0; kk < 24; ++kk) {
        int k = g * 24 + kk;
        a2 = fmaf(xsh[wv][k], wp2[k * OUT_F], a2);
    }
    a2 += __shfl_xor(a2, 16);
    a2 += __shfl_xor(a2, 32);
    float ps = a2 * attS2[o2];
    float pd = a2 * attD2[o2];
#pragma unroll
    for (int o = 1; o < 16; o <<= 1) {
        ps += __shfl_xor(ps, o);
        pd += __shfl_xor(pd, o);
    }
    if (lane == 0) { aS2[n] = ps; aD2[n] = pd; }
    if (lane < 16) h2[n * OUT_F + o2] = a2;
}

// ===== Layer 2 fused softmax+aggregate+bias+log_softmax: 1 wave/node, f4 LDS =====
__global__ __launch_bounds__(256) void l2_node(const int2* __restrict__ rw,
                                               const int* __restrict__ csr,
                                               const float* __restrict__ h2,
                                               const float* __restrict__ aS2,
                                               const float* __restrict__ aD2,
                                               const float* __restrict__ bias2,
                                               float* __restrict__ out) {
    __shared__ float lds[4][66][2];      // [wave][entry(+pad, 16B rows)][{e, s*16}]
    int wv = threadIdx.x >> 6, lane = threadIdx.x & 63;
    int n = blockIdx.x * 4 + wv;
    int2 r2 = ntload_i2(&rw[n]);
    int rs = r2.x, re = r2.y;
    float adn = aD2[n];
    int g = lane >> 4, fl = lane & 15;
    float den = 0.f, acc = 0.f;
    for (int base = rs; base < re; base += 64) {
        int j = base + lane;
        float e = 0.f;
        float sf = __int_as_float(0);
        if (j < re) {
            int s = ntload_i(&csr[j]);
            e = __expf(lrelu(aS2[s] + adn));
            sf = __int_as_float(s * OUT_F);
        }
        den += e;
        lds[wv][lane][0] = e;
        lds[wv][lane][1] = sf;
        int cnt = min(64, re - base);
#pragma unroll
        for (int b2 = 0; b2 < 2; ++b2) {
            int j0 = g * 16 + b2 * 8;
            if (j0 < cnt) {
                float4 q[4];
#pragma unroll
                for (int u2 = 0; u2 < 4; ++u2)
                    q[u2] = *(const float4*)&lds[wv][j0 + 2 * u2][0];
                float hv[8];
#pragma unroll
                for (int u2 = 0; u2 < 4; ++u2) {
                    hv[2 * u2]     = h2[__float_as_int(q[u2].y) + fl];
                    hv[2 * u2 + 1] = h2[__float_as_int(q[u2].w) + fl];
                }
#pragma unroll
                for (int u2 = 0; u2 < 4; ++u2) {
                    acc = fmaf(hv[2 * u2],     q[u2].x, acc);
                    acc = fmaf(hv[2 * u2 + 1], q[u2].z, acc);
                }
            }
        }
    }
    den = wave_sum(den);
    acc += __shfl_xor(acc, 16);
    acc += __shfl_xor(acc, 32);
    float v = acc / den + bias2[fl];
    float mm = v;
#pragma unroll
    for (int o = 1; o < 16; o <<= 1) mm = fmaxf(mm, __shfl_xor(mm, o));
    float se = __expf(v - mm);
#pragma unroll
    for (int o = 1; o < 16; o <<= 1) se += __shfl_xor(se, o);
    float lse = mm + logf(se);
    if (lane < 16) __builtin_nontemporal_store(v - lse, &out[n * OUT_F + fl]);
}

extern "C" void kernel_launch(void* const* d_in, const int* in_sizes, int n_in,
                              void* d_out, int out_size, void* d_ws, size_t ws_size,
                              hipStream_t stream) {
    const float* x      = (const float*)d_in[0];
    const int*   ei     = (const int*)  d_in[1];
    const float* W1     = (const float*)d_in[2];
    const float* attS1  = (const float*)d_in[3];
    const float* attD1  = (const float*)d_in[4];
    const float* bias1  = (const float*)d_in[5];
    const float* W2     = (const float*)d_in[6];
    const float* attS2  = (const float*)d_in[7];
    const float* attD2  = (const float*)d_in[8];
    const float* bias2  = (const float*)d_in[9];
    const int* src = ei;
    const int* dst = ei + N_EDGES;
    float* out = (float*)d_out;
    (void)in_sizes; (void)n_in; (void)out_size; (void)ws_size;

    // ---- workspace layout ----
    char* wsb = (char*)d_ws;
    size_t off = 0;
    int* gcur   = (int*)(wsb + off); off += 256 * 4;          // zero region
    size_t zero_bytes = off;
    int2* rw    = (int2*)(wsb + off); off += (size_t)N_NODES * 8;
    off = (off + 15) & ~(size_t)15;
    int* csr    = (int*)(wsb + off); off += (size_t)NBUCK * CAP * 4;
    off = (off + 15) & ~(size_t)15;
    int* bedge  = (int*)(wsb + off); off += (size_t)NBUCK * CAP * 4;
    off = (off + 15) & ~(size_t)15;
    unsigned char* h1 = (unsigned char*)(wsb + off); off += (size_t)N_NODES * C1;
    off = (off + 15) & ~(size_t)15;
    float* aS1p = (float*)(wsb + off); off += (size_t)N_NODES * 4 * 4;
    float* aD1p = (float*)(wsb + off); off += (size_t)N_NODES * 4 * 4;
    off = (off + 15) & ~(size_t)15;
    float* h2   = (float*)(wsb + off); off += (size_t)N_NODES * OUT_F * 4;
    float* aS2  = (float*)(wsb + off); off += (size_t)N_NODES * 4;
    float* aD2  = (float*)(wsb + off); off += (size_t)N_NODES * 4;

    hipMemsetAsync(d_ws, 0, zero_bytes, stream);

    // phase1: CSR bucket pass ∥ layer-1 GEMM (independent, one dispatch)
    phase1<<<NBLK_B + NBLK_G, 256, 0, stream>>>(src, dst, gcur, bedge,
                                                x, W1, attS1, attD1, h1, aS1p, aD1p);
    k_finalize<<<NBUCK, 256, 0, stream>>>(gcur, bedge, rw, csr);

    int nbn = N_NODES / 4;   // 12500, exact
    l1_node<<<nbn, 256, 0, stream>>>(rw, csr, h1, aS1p, aD1p, bias1,
                                     W2, attS2, attD2, h2, aS2, aD2);
    l2_node<<<nbn, 256, 0, stream>>>(rw, csr, h2, aS2, aD2, bias2, out);
}